// Round 7
// baseline (1703.899 us; speedup 1.0000x reference)
//
#include <hip/hip_runtime.h>
#include <stdint.h>

#define N_NODES 50000
#define N_EDGES 1600000
#define ETOT    (N_EDGES + N_NODES)
#define FN 16
#define FE 8
#define HID 64
#define NGR 8
#define NEG_ATT 0.2f
#define NEG_ACT 0.01f
#define EPS_BN 1e-5f
#define MEAN_BLOCKS 512
#define SELF_FLAG 0x40000000
#define SRC_MASK  0x3FFFFFFF
#define SCAN_BLOCKS 196   // ceil(50000/256)

typedef __attribute__((ext_vector_type(8))) short short8;
typedef __attribute__((ext_vector_type(4))) float f32x4;

__device__ __forceinline__ float bf2f(unsigned short u) {
  union { unsigned int i; float f; } c; c.i = ((unsigned int)u) << 16; return c.f;
}
__device__ __forceinline__ unsigned short f2bf(float f) {
  union { float f; unsigned int i; } c; c.f = f;
  unsigned int r = c.i + 0x7FFFu + ((c.i >> 16) & 1u);
  return (unsigned short)(r >> 16);
}
__device__ __forceinline__ float lrelu(float x, float s) { return x > 0.f ? x : s * x; }

template <int HW>
__device__ __forceinline__ float headsum(float mm) {
#pragma unroll
  for (int o = 1; o < HW; o <<= 1) mm += __shfl_xor(mm, o, 64);
  return mm;
}

// ---------------- K1: xh = x @ node_W + node_b ----------------
__global__ __launch_bounds__(256) void k_node_embed(
    const float* __restrict__ x, const float* __restrict__ W,
    const float* __restrict__ b, float* __restrict__ xh) {
  __shared__ float sW[FN * HID];
  int t = threadIdx.x;
  for (int i = t; i < FN * HID; i += 256) sW[i] = W[i];
  __syncthreads();
  int j = t & 63;
  int v = blockIdx.x * 4 + (t >> 6);
  const float* xr = x + v * FN;
  float acc = b[j];
#pragma unroll
  for (int k = 0; k < FN; ++k) acc += xr[k] * sW[k * HID + j];
  xh[v * HID + j] = acc;
}

// ---------------- K2: in-degree histogram over dst ----------------
__global__ __launch_bounds__(256) void k_hist(const int* __restrict__ ei,
                                              int* __restrict__ counts) {
  int i = blockIdx.x * blockDim.x + threadIdx.x;
  int stride = gridDim.x * blockDim.x;
  for (; i < N_EDGES; i += stride) atomicAdd(&counts[ei[N_EDGES + i]], 1);
}

// ---------------- K3: 3-phase parallel exclusive scan ----------------
__global__ __launch_bounds__(256) void k_scanA(const int* __restrict__ counts,
                                               int* __restrict__ row_ptr,
                                               int* __restrict__ blocksum) {
  __shared__ int s[256];
  int t = threadIdx.x;
  int v = blockIdx.x * 256 + t;
  int val = (v < N_NODES) ? counts[v] + 1 : 0;   // +1 self loop
  s[t] = val; __syncthreads();
  for (int off = 1; off < 256; off <<= 1) {
    int add = (t >= off) ? s[t - off] : 0;
    __syncthreads();
    s[t] += add;
    __syncthreads();
  }
  if (v < N_NODES) row_ptr[v] = s[t] - val;      // block-local exclusive
  if (t == 255) blocksum[blockIdx.x] = s[255];
}

__global__ __launch_bounds__(256) void k_scanB(const int* __restrict__ blocksum,
                                               int* __restrict__ blockoff,
                                               int* __restrict__ row_ptr) {
  __shared__ int s[256];
  int t = threadIdx.x;
  int val = (t < SCAN_BLOCKS) ? blocksum[t] : 0;
  s[t] = val; __syncthreads();
  for (int off = 1; off < 256; off <<= 1) {
    int add = (t >= off) ? s[t - off] : 0;
    __syncthreads();
    s[t] += add;
    __syncthreads();
  }
  if (t < SCAN_BLOCKS) blockoff[t] = s[t] - val;
  if (t == 255) row_ptr[N_NODES] = s[255];
}

__global__ __launch_bounds__(256) void k_scanC(int* __restrict__ row_ptr,
                                               int* __restrict__ fill,
                                               const int* __restrict__ blockoff) {
  int t = threadIdx.x;
  int v = blockIdx.x * 256 + t;
  if (v < N_NODES) {
    int rp = row_ptr[v] + blockoff[blockIdx.x];
    row_ptr[v] = rp;
    fill[v] = rp;
  }
}

// ------- K4: scatter (src|flag, perm) 8B records, dst-sorted -------
__global__ __launch_bounds__(256) void k_scatter(const int* __restrict__ ei,
                                                 int* __restrict__ fill,
                                                 int2* __restrict__ srcperm) {
  int i = blockIdx.x * blockDim.x + threadIdx.x;
  int stride = gridDim.x * blockDim.x;
  for (; i < ETOT; i += stride) {
    if (i < N_EDGES) {
      int d = ei[N_EDGES + i];
      int pos = atomicAdd(&fill[d], 1);
      srcperm[pos] = make_int2(ei[i], i);
    } else {
      int v = i - N_EDGES;
      int pos = atomicAdd(&fill[v], 1);
      srcperm[pos] = make_int2(v | SELF_FLAG, 0);
    }
  }
}

// ------- K4b: edge_attr fp32 -> bf16, original order (coalesced) -------
__global__ __launch_bounds__(256) void k_attr_cvt(const float* __restrict__ eattr,
                                                  unsigned short* __restrict__ attr_bf) {
  int idx = blockIdx.x * 256 + threadIdx.x;   // over N_EDGES*FE/4
  float4 a = ((const float4*)eattr)[idx];
  unsigned int lo = (unsigned int)f2bf(a.x) | ((unsigned int)f2bf(a.y) << 16);
  unsigned int hi = (unsigned int)f2bf(a.z) | ((unsigned int)f2bf(a.w) << 16);
  ((int2*)attr_bf)[idx] = make_int2((int)lo, (int)hi);
}

// ------- K5: mean of ea over real edges — LDS-staged, coalesced -------
__global__ __launch_bounds__(256) void k_meanp(const float* __restrict__ eattr,
                                               const float* __restrict__ eW,
                                               const float* __restrict__ eb,
                                               float* __restrict__ partial) {
  __shared__ float sA[256 * FE];
  __shared__ float sred[256];
  int t = threadIdx.x; int j = t & 63; int w = t >> 6;
  float Wj[8];
#pragma unroll
  for (int k = 0; k < 8; ++k) Wj[k] = eW[k * HID + j];
  float bj = eb[j], msum = 0.f;
  const int TILES = N_EDGES / 256;
  for (int tile = blockIdx.x; tile < TILES; tile += gridDim.x) {
    __syncthreads();
    const float4* src = (const float4*)(eattr + (size_t)tile * 256 * FE);
    ((float4*)sA)[t] = src[t];
    ((float4*)sA)[t + 256] = src[t + 256];
    __syncthreads();
#pragma unroll 8
    for (int e = 0; e < 64; ++e) {
      const float4* ar = (const float4*)(sA + (w * 64 + e) * FE);
      float4 A0 = ar[0], A1 = ar[1];
      float acc = bj + A0.x * Wj[0] + A0.y * Wj[1] + A0.z * Wj[2] + A0.w * Wj[3]
                     + A1.x * Wj[4] + A1.y * Wj[5] + A1.z * Wj[6] + A1.w * Wj[7];
      msum += lrelu(acc, NEG_ACT);
    }
  }
  sred[t] = msum; __syncthreads();
  if (w == 0)
    partial[blockIdx.x * HID + j] = sred[j] + sred[j + 64] + sred[j + 128] + sred[j + 192];
}

__global__ __launch_bounds__(256) void k_mean(const float* __restrict__ partial,
                                              float* __restrict__ mean) {
  __shared__ float sred[256];
  int t = threadIdx.x; int j = t & 63; int w = t >> 6;
  float s = 0.f;
  for (int bk = w; bk < MEAN_BLOCKS; bk += 4) s += partial[bk * HID + j];
  sred[t] = s; __syncthreads();
  if (w == 0)
    mean[j] = (sred[j] + sred[j + 64] + sred[j + 128] + sred[j + 192]) / (float)N_EDGES;
}

// ------- K6: e_self = mean(ea) @ Wed (fp32 exact) -------
__global__ void k_eself(const float* __restrict__ meanv,
                        const float* __restrict__ Wed,
                        float* __restrict__ e_self) {
  int j = threadIdx.x;
  float s = 0.f;
  for (int k = 0; k < HID; ++k) s += meanv[k] * Wed[k * HID + j];
  e_self[j] = s;
}

// ------- K7: xl(bf16) = xh@Wl+bl, xr(f32) = xh@Wr+br -------
__global__ __launch_bounds__(256) void k_xlr(const float* __restrict__ xh,
                                             const float* __restrict__ Wl,
                                             const float* __restrict__ bl,
                                             const float* __restrict__ Wr,
                                             const float* __restrict__ br,
                                             unsigned short* __restrict__ xl_bf,
                                             float* __restrict__ xr) {
  __shared__ float sWl[HID * HID], sWr[HID * HID];
  __shared__ float srow[4][HID];
  int t = threadIdx.x;
  for (int i = t; i < HID * HID; i += 256) { sWl[i] = Wl[i]; sWr[i] = Wr[i]; }
  __syncthreads();
  int j = t & 63; int w = t >> 6;
  int v = blockIdx.x * 4 + w;
  srow[w][j] = xh[v * HID + j];
  __syncthreads();
  float accL = bl[j], accR = br[j];
#pragma unroll
  for (int k = 0; k < HID; ++k) {
    float xk = srow[w][k];
    accL += xk * sWl[k * HID + j];
    accR += xk * sWr[k * HID + j];
  }
  xl_bf[v * HID + j] = f2bf(accL);
  xr[v * HID + j] = accR;
}

// ======= K8: FUSED attention, guarded groups-of-4, LDS slab union =======
template <int HW>
__global__ __launch_bounds__(256) void k_attn_f(
    const unsigned short* __restrict__ xl_bf, const float* __restrict__ xr,
    const unsigned short* __restrict__ attr_bf,
    const int2* __restrict__ srcperm, const int* __restrict__ row_ptr,
    const float* __restrict__ eW, const float* __restrict__ eb,
    const float* __restrict__ Wed, const float* __restrict__ e_self,
    const float* __restrict__ att, const float* __restrict__ cb,
    float* __restrict__ xo) {
  // LDS: 4 per-wave slabs of 4224 B. Slab = T1 [16][72] bf16 (2304 B) then,
  // aliased, T2 [16][66] f32 (4224 B). Preamble weights alias slabs region too.
  __shared__ __align__(16) char smem[16896];
  unsigned short* sWed = (unsigned short*)smem;                 // [64*64] bf16
  unsigned short* sEw  = (unsigned short*)(smem + 8192);        // [8*64]
  float*          sEb  = (float*)(smem + 8192 + 1024);          // [64]

  int t = threadIdx.x;
  for (int i = t; i < HID * HID; i += 256) sWed[i] = f2bf(Wed[i]);
  for (int i = t; i < FE * HID; i += 256) sEw[i] = f2bf(eW[i]);
  if (t < HID) sEb[t] = eb[t];
  __syncthreads();

  int lane = t & 63, w = t >> 6, l15 = lane & 15, lg = lane >> 4;

  // Wed B-frags: B[k][col], col=l15(+16jc), k=8lg+i (+32 for kh=1)
  short8 bW[4][2];
#pragma unroll
  for (int jc = 0; jc < 4; ++jc)
#pragma unroll
    for (int kh = 0; kh < 2; ++kh)
#pragma unroll
      for (int i = 0; i < 8; ++i)
        bW[jc][kh][i] = (short)sWed[(8 * lg + i + 32 * kh) * HID + jc * 16 + l15];
  // eW B-frags (K padded 8->32: only lg==0 holds real k=0..7)
  short8 bE[4] = {};
  if (lg == 0)
#pragma unroll
    for (int jc = 0; jc < 4; ++jc)
#pragma unroll
      for (int i = 0; i < 8; ++i)
        bE[jc][i] = (short)sEw[i * HID + jc * 16 + l15];
  float biasv[4];
#pragma unroll
  for (int jc = 0; jc < 4; ++jc) biasv[jc] = sEb[jc * 16 + l15];
  __syncthreads();   // all waves done with weights before slabs overwrite

  unsigned short* T1w = (unsigned short*)(smem + w * 4224);  // [16][72] bf16
  float*          T2w = (float*)(smem + w * 4224);           // [16][66] f32

  int v = blockIdx.x * 4 + w;
  if (v >= N_NODES) return;

  float xrv = xr[v * HID + lane];
  float attj = att[lane];
  float esj = e_self[lane];
  float cbj = cb[lane];
  int beg = row_ptr[v], end = row_ptr[v + 1];
  float M = -3.0e38f, S = 0.f, acc = 0.f;

  for (int base = beg; base < end; base += 16) {
    int cnt = end - base; if (cnt > 16) cnt = 16;   // wave-uniform
    int eidx = base + l15; if (eidx >= end) eidx = end - 1;
    int2 sp = srcperm[eidx];
    unsigned long long selfm = __ballot(sp.x & SELF_FLAG);  // bits 0..15 valid

    // ---- gathers (guarded groups of 4), issued early to hide latency
    float xls[16];
#define GATHER1(i) { int raw = __builtin_amdgcn_readlane(sp.x, (i)); \
      xls[(i)] = bf2f(xl_bf[(unsigned)(raw & SRC_MASK) * 64u + (unsigned)lane]); }
#define GATHER4(G) if (cnt > 4*(G)) { GATHER1(4*(G)) GATHER1(4*(G)+1) \
                                      GATHER1(4*(G)+2) GATHER1(4*(G)+3) }
    GATHER4(0) GATHER4(1) GATHER4(2) GATHER4(3)

    // ---- MFMA1: ea = attr(16x8, K-pad 32) @ eW -> D[edge=4lg+i][ch=jc16+l15]
    short8 a0 = {};
    if (lg == 0 && !(sp.x & SELF_FLAG))
      a0 = *(const short8*)(attr_bf + (size_t)sp.y * FE);
    f32x4 accE[4];
#pragma unroll
    for (int jc = 0; jc < 4; ++jc) {
      f32x4 z = {};
      accE[jc] = __builtin_amdgcn_mfma_f32_16x16x32_bf16(a0, bE[jc], z, 0, 0, 0);
    }
#pragma unroll
    for (int jc = 0; jc < 4; ++jc)
#pragma unroll
      for (int i = 0; i < 4; ++i)
        T1w[(4 * lg + i) * 72 + jc * 16 + l15] =
            f2bf(lrelu(accE[jc][i] + biasv[jc], NEG_ACT));
    __builtin_amdgcn_wave_barrier();
    asm volatile("s_waitcnt lgkmcnt(0)" ::: "memory");
    __builtin_amdgcn_sched_barrier(0);

    // ---- MFMA2: e = ea(16x64) @ Wed -> T2 (T2 aliases T1: drain reads first)
    short8 A0 = *(const short8*)&T1w[l15 * 72 + 8 * lg];
    short8 A1 = *(const short8*)&T1w[l15 * 72 + 32 + 8 * lg];
    asm volatile("s_waitcnt lgkmcnt(0)" ::: "memory");
    __builtin_amdgcn_sched_barrier(0);
    f32x4 acc2[4];
#pragma unroll
    for (int jc = 0; jc < 4; ++jc) {
      f32x4 z = {};
      acc2[jc] = __builtin_amdgcn_mfma_f32_16x16x32_bf16(A0, bW[jc][0], z, 0, 0, 0);
      acc2[jc] = __builtin_amdgcn_mfma_f32_16x16x32_bf16(A1, bW[jc][1], acc2[jc], 0, 0, 0);
    }
#pragma unroll
    for (int jc = 0; jc < 4; ++jc)
#pragma unroll
      for (int i = 0; i < 4; ++i)
        T2w[(4 * lg + i) * 66 + jc * 16 + l15] = acc2[jc][i];
    __builtin_amdgcn_wave_barrier();
    asm volatile("s_waitcnt lgkmcnt(0)" ::: "memory");
    __builtin_amdgcn_sched_barrier(0);

    // ---- scores (guarded groups of 4), self-flag via scalar ballot mask
    float r[16];
#define SCORE1(i) { \
      float e = ((selfm >> (i)) & 1ull) ? esj : T2w[(i) * 66 + lane]; \
      float mm = lrelu(xls[(i)] + xrv + e, NEG_ATT) * attj; \
      mm = headsum<HW>(mm); \
      r[(i)] = ((i) < cnt) ? mm : -3.0e38f; }
#define SCORE4(G) if (cnt > 4*(G)) { SCORE1(4*(G)) SCORE1(4*(G)+1) \
                                     SCORE1(4*(G)+2) SCORE1(4*(G)+3) }
    SCORE4(0) SCORE4(1) SCORE4(2) SCORE4(3)

    // ---- single online-softmax merge (one rescale per tile)
    float mx = -3.0e38f;
#define MAX4(G) if (cnt > 4*(G)) { mx = fmaxf(fmaxf(mx, fmaxf(r[4*(G)], r[4*(G)+1])), \
                                              fmaxf(r[4*(G)+2], r[4*(G)+3])); }
    MAX4(0) MAX4(1) MAX4(2) MAX4(3)
    float Mn = fmaxf(M, mx);
    float sc = __expf(M - Mn);
    acc *= sc; S *= sc;
#define ACC1(i) { float wi = __expf(r[(i)] - Mn); S += wi; acc += wi * xls[(i)]; }
#define ACC4(G) if (cnt > 4*(G)) { ACC1(4*(G)) ACC1(4*(G)+1) ACC1(4*(G)+2) ACC1(4*(G)+3) }
    ACC4(0) ACC4(1) ACC4(2) ACC4(3)
    M = Mn;
    __builtin_amdgcn_wave_barrier();
  }
  xo[v * HID + lane] = acc / S + cbj;
}

// ---------------- K10: BN stats ----------------
__global__ __launch_bounds__(256) void k_bnstats(const float* __restrict__ xo,
                                                 float* __restrict__ bns) {
  __shared__ float s1[256], s2[256];
  int t = threadIdx.x; int j = t & 63; int r = t >> 6;
  float sum = 0.f, sq = 0.f;
  int stride = gridDim.x * 4;
  for (int v = blockIdx.x * 4 + r; v < N_NODES; v += stride) {
    float x = xo[v * HID + j];
    sum += x; sq += x * x;
  }
  s1[t] = sum; s2[t] = sq; __syncthreads();
  if (r == 0) {
    atomicAdd(&bns[j], s1[j] + s1[j + 64] + s1[j + 128] + s1[j + 192]);
    atomicAdd(&bns[64 + j], s2[j] + s2[j + 64] + s2[j + 128] + s2[j + 192]);
  }
}

// ---------------- K11: BN apply + LeakyReLU (in-place safe) ----------------
__global__ __launch_bounds__(256) void k_bnapply(const float* __restrict__ xo,
                                                 const float* __restrict__ bns,
                                                 const float* __restrict__ g,
                                                 const float* __restrict__ b,
                                                 float* __restrict__ xh) {
  int tid = blockIdx.x * 256 + threadIdx.x;
  int j = tid & 63;
  int v = tid >> 6;
  if (v >= N_NODES) return;
  const float invN = 1.f / (float)N_NODES;
  float mu = bns[j] * invN;
  float var = bns[64 + j] * invN - mu * mu;
  var = fmaxf(var, 0.f);
  float y = (xo[v * HID + j] - mu) * rsqrtf(var + EPS_BN) * g[j] + b[j];
  xh[v * HID + j] = lrelu(y, NEG_ACT);
}

// ---------------- K12: global add pool ----------------
__global__ __launch_bounds__(256) void k_pool(const float* __restrict__ xh,
                                              const int* __restrict__ batch,
                                              float* __restrict__ pooled) {
  __shared__ float lacc[4][NGR][HID];
  int t = threadIdx.x; int j = t & 63; int r = t >> 6;
  float a[NGR];
#pragma unroll
  for (int gg = 0; gg < NGR; ++gg) a[gg] = 0.f;
  int stride = gridDim.x * 4;
  for (int v = blockIdx.x * 4 + r; v < N_NODES; v += stride) {
    int g = batch[v];
    float x = xh[v * HID + j];
#pragma unroll
    for (int gg = 0; gg < NGR; ++gg) a[gg] += (g == gg) ? x : 0.f;
  }
#pragma unroll
  for (int gg = 0; gg < NGR; ++gg) lacc[r][gg][j] = a[gg];
  __syncthreads();
  if (r == 0) {
#pragma unroll
    for (int gg = 0; gg < NGR; ++gg)
      atomicAdd(&pooled[gg * HID + j],
                lacc[0][gg][j] + lacc[1][gg][j] + lacc[2][gg][j] + lacc[3][gg][j]);
  }
}

// ---------------- K13: readout ----------------
__global__ __launch_bounds__(256) void k_readout(const float* __restrict__ pooled,
                                                 const float* __restrict__ W1,
                                                 const float* __restrict__ b1,
                                                 const float* __restrict__ W2,
                                                 const float* __restrict__ b2,
                                                 float* __restrict__ out) {
  __shared__ float hid[NGR][32];
  int t = threadIdx.x;
  int g = t >> 5, q = t & 31;
  float acc = b1[q];
  for (int k = 0; k < HID; ++k) acc += pooled[g * HID + k] * W1[k * 32 + q];
  hid[g][q] = lrelu(acc, NEG_ACT);
  __syncthreads();
  if (t < NGR) {
    float o = b2[0];
    for (int q2 = 0; q2 < 32; ++q2) o += hid[t][q2] * W2[q2];
    out[t] = o;
  }
}

extern "C" void kernel_launch(void* const* d_in, const int* in_sizes, int n_in,
                              void* d_out, int out_size, void* d_ws, size_t ws_size,
                              hipStream_t stream) {
  (void)in_sizes; (void)n_in; (void)out_size; (void)ws_size;
  const float* x      = (const float*)d_in[0];
  const int*   ei     = (const int*)d_in[1];
  const float* eattr  = (const float*)d_in[2];
  const int*   batch  = (const int*)d_in[3];
  const float* node_W = (const float*)d_in[4];
  const float* node_b = (const float*)d_in[5];
  const float* eemb_W = (const float*)d_in[6];
  const float* eemb_b = (const float*)d_in[7];
  const float* ro1_W  = (const float*)d_in[35];
  const float* ro1_b  = (const float*)d_in[36];
  const float* ro2_W  = (const float*)d_in[37];
  const float* ro2_b  = (const float*)d_in[38];
  float* out = (float*)d_out;

  char* p = (char*)d_ws;
  auto alloc = [&](size_t bytes) {
    char* r = p;
    p += (bytes + 255) & ~(size_t)255;
    return r;
  };
  // --- zero zone (single memset) ---
  int*   counts = (int*)alloc((size_t)N_NODES * 4);
  float* bns    = (float*)alloc(3 * 128 * 4);
  float* pooled = (float*)alloc(NGR * HID * 4);
  size_t zero_bytes = (size_t)(p - (char*)d_ws);
  // --- fixed buffers (each written before read every call) ---
  int*   row_ptr  = (int*)alloc((size_t)(N_NODES + 1) * 4);
  int*   fill     = (int*)alloc((size_t)N_NODES * 4);
  int*   blocksum = (int*)alloc((size_t)SCAN_BLOCKS * 4);
  int*   blockoff = (int*)alloc((size_t)SCAN_BLOCKS * 4);
  int2*  srcperm  = (int2*)alloc((size_t)ETOT * 8);
  unsigned short* attr_bf = (unsigned short*)alloc((size_t)N_EDGES * FE * 2);
  float* partial = (float*)alloc((size_t)MEAN_BLOCKS * HID * 4);
  float* meanv   = (float*)alloc(HID * 4);
  float* e_self  = (float*)alloc(HID * 4);
  float* xh      = (float*)alloc((size_t)N_NODES * HID * 4);
  unsigned short* xl_bf = (unsigned short*)alloc((size_t)N_NODES * HID * 2);
  float* xr      = (float*)alloc((size_t)N_NODES * HID * 4);
  float* xo      = xh;   // alias: xh is dead between k_xlr and k_bnapply

  hipMemsetAsync(d_ws, 0, zero_bytes, stream);

  k_node_embed<<<N_NODES / 4, 256, 0, stream>>>(x, node_W, node_b, xh);
  k_hist<<<1024, 256, 0, stream>>>(ei, counts);
  k_scanA<<<SCAN_BLOCKS, 256, 0, stream>>>(counts, row_ptr, blocksum);
  k_scanB<<<1, 256, 0, stream>>>(blocksum, blockoff, row_ptr);
  k_scanC<<<SCAN_BLOCKS, 256, 0, stream>>>(row_ptr, fill, blockoff);
  k_scatter<<<1024, 256, 0, stream>>>(ei, fill, srcperm);
  k_attr_cvt<<<N_EDGES * FE / 4 / 256, 256, 0, stream>>>(eattr, attr_bf);
  k_meanp<<<MEAN_BLOCKS, 256, 0, stream>>>(eattr, eemb_W, eemb_b, partial);
  k_mean<<<1, 256, 0, stream>>>(partial, meanv);

  const int ablocks = (N_NODES + 3) / 4;
  for (int L = 0; L < 3; ++L) {
    const float* Wl  = (const float*)d_in[8 + 9 * L + 0];
    const float* bl  = (const float*)d_in[8 + 9 * L + 1];
    const float* Wr  = (const float*)d_in[8 + 9 * L + 2];
    const float* br  = (const float*)d_in[8 + 9 * L + 3];
    const float* Wed = (const float*)d_in[8 + 9 * L + 4];
    const float* att = (const float*)d_in[8 + 9 * L + 5];
    const float* cb  = (const float*)d_in[8 + 9 * L + 6];
    const float* g   = (const float*)d_in[8 + 9 * L + 7];
    const float* bt  = (const float*)d_in[8 + 9 * L + 8];
    k_xlr<<<N_NODES / 4, 256, 0, stream>>>(xh, Wl, bl, Wr, br, xl_bf, xr);
    k_eself<<<1, 64, 0, stream>>>(meanv, Wed, e_self);
    if (L < 2)
      k_attn_f<16><<<ablocks, 256, 0, stream>>>(xl_bf, xr, attr_bf, srcperm, row_ptr,
                                                eemb_W, eemb_b, Wed, e_self, att, cb, xo);
    else
      k_attn_f<64><<<ablocks, 256, 0, stream>>>(xl_bf, xr, attr_bf, srcperm, row_ptr,
                                                eemb_W, eemb_b, Wed, e_self, att, cb, xo);
    k_bnstats<<<256, 256, 0, stream>>>(xo, bns + L * 128);
    k_bnapply<<<N_NODES * HID / 256, 256, 0, stream>>>(xo, bns + L * 128, g, bt, xh);
  }

  k_pool<<<64, 256, 0, stream>>>(xh, batch, pooled);
  k_readout<<<1, 256, 0, stream>>>(pooled, ro1_W, ro1_b, ro2_W, ro2_b, out);
}

// Round 8
// 1347.602 us; speedup vs baseline: 1.2644x; 1.2644x over previous
//
#include <hip/hip_runtime.h>
#include <stdint.h>

#define N_NODES 50000
#define N_EDGES 1600000
#define ETOT    (N_EDGES + N_NODES)
#define FN 16
#define FE 8
#define HID 64
#define NGR 8
#define NEG_ATT 0.2f
#define NEG_ACT 0.01f
#define EPS_BN 1e-5f
#define MEAN_BLOCKS 512
#define SELF_FLAG 0x40000000
#define SRC_MASK  0x3FFFFFFF
#define SCAN_BLOCKS 196   // ceil(50000/256)

typedef __attribute__((ext_vector_type(8))) short short8;
typedef __attribute__((ext_vector_type(4))) float f32x4;

__device__ __forceinline__ float bf2f(unsigned short u) {
  union { unsigned int i; float f; } c; c.i = ((unsigned int)u) << 16; return c.f;
}
__device__ __forceinline__ unsigned short f2bf(float f) {
  union { float f; unsigned int i; } c; c.f = f;
  unsigned int r = c.i + 0x7FFFu + ((c.i >> 16) & 1u);
  return (unsigned short)(r >> 16);
}
__device__ __forceinline__ float lrelu(float x, float s) { return x > 0.f ? x : s * x; }

// ---------------- K1: xh = x @ node_W + node_b ----------------
__global__ __launch_bounds__(256) void k_node_embed(
    const float* __restrict__ x, const float* __restrict__ W,
    const float* __restrict__ b, float* __restrict__ xh) {
  __shared__ float sW[FN * HID];
  int t = threadIdx.x;
  for (int i = t; i < FN * HID; i += 256) sW[i] = W[i];
  __syncthreads();
  int j = t & 63;
  int v = blockIdx.x * 4 + (t >> 6);
  const float* xr = x + v * FN;
  float acc = b[j];
#pragma unroll
  for (int k = 0; k < FN; ++k) acc += xr[k] * sW[k * HID + j];
  xh[v * HID + j] = acc;
}

// ---------------- K2: in-degree histogram over dst ----------------
__global__ __launch_bounds__(256) void k_hist(const int* __restrict__ ei,
                                              int* __restrict__ counts) {
  int i = blockIdx.x * blockDim.x + threadIdx.x;
  int stride = gridDim.x * blockDim.x;
  for (; i < N_EDGES; i += stride) atomicAdd(&counts[ei[N_EDGES + i]], 1);
}

// ---------------- K3: 3-phase parallel exclusive scan ----------------
__global__ __launch_bounds__(256) void k_scanA(const int* __restrict__ counts,
                                               int* __restrict__ row_ptr,
                                               int* __restrict__ blocksum) {
  __shared__ int s[256];
  int t = threadIdx.x;
  int v = blockIdx.x * 256 + t;
  int val = (v < N_NODES) ? counts[v] + 1 : 0;   // +1 self loop
  s[t] = val; __syncthreads();
  for (int off = 1; off < 256; off <<= 1) {
    int add = (t >= off) ? s[t - off] : 0;
    __syncthreads();
    s[t] += add;
    __syncthreads();
  }
  if (v < N_NODES) row_ptr[v] = s[t] - val;
  if (t == 255) blocksum[blockIdx.x] = s[255];
}

__global__ __launch_bounds__(256) void k_scanB(const int* __restrict__ blocksum,
                                               int* __restrict__ blockoff,
                                               int* __restrict__ row_ptr) {
  __shared__ int s[256];
  int t = threadIdx.x;
  int val = (t < SCAN_BLOCKS) ? blocksum[t] : 0;
  s[t] = val; __syncthreads();
  for (int off = 1; off < 256; off <<= 1) {
    int add = (t >= off) ? s[t - off] : 0;
    __syncthreads();
    s[t] += add;
    __syncthreads();
  }
  if (t < SCAN_BLOCKS) blockoff[t] = s[t] - val;
  if (t == 255) row_ptr[N_NODES] = s[255];
}

__global__ __launch_bounds__(256) void k_scanC(int* __restrict__ row_ptr,
                                               int* __restrict__ fill,
                                               const int* __restrict__ blockoff) {
  int t = threadIdx.x;
  int v = blockIdx.x * 256 + t;
  if (v < N_NODES) {
    int rp = row_ptr[v] + blockoff[blockIdx.x];
    row_ptr[v] = rp;
    fill[v] = rp;
  }
}

// ------- K4: scatter (src|flag, perm) 8B records, dst-sorted -------
__global__ __launch_bounds__(256) void k_scatter(const int* __restrict__ ei,
                                                 int* __restrict__ fill,
                                                 int2* __restrict__ srcperm) {
  int i = blockIdx.x * blockDim.x + threadIdx.x;
  int stride = gridDim.x * blockDim.x;
  for (; i < ETOT; i += stride) {
    if (i < N_EDGES) {
      int d = ei[N_EDGES + i];
      int pos = atomicAdd(&fill[d], 1);
      srcperm[pos] = make_int2(ei[i], i);
    } else {
      int v = i - N_EDGES;
      int pos = atomicAdd(&fill[v], 1);
      srcperm[pos] = make_int2(v | SELF_FLAG, 0);
    }
  }
}

// ------- K4c: dst per sorted edge (coalesced segment writes) -------
__global__ __launch_bounds__(256) void k_filldst(const int* __restrict__ row_ptr,
                                                 int* __restrict__ dst_s) {
  int t = threadIdx.x; int lane = t & 63; int w = t >> 6;
  int v = blockIdx.x * 4 + w;
  if (v >= N_NODES) return;
  int beg = row_ptr[v], end = row_ptr[v + 1];
  for (int p = beg + lane; p < end; p += 64) dst_s[p] = v;
}

// ------- K5: mean of ea over real edges — LDS-staged, coalesced -------
__global__ __launch_bounds__(256) void k_meanp(const float* __restrict__ eattr,
                                               const float* __restrict__ eW,
                                               const float* __restrict__ eb,
                                               float* __restrict__ partial) {
  __shared__ float sA[256 * FE];
  __shared__ float sred[256];
  int t = threadIdx.x; int j = t & 63; int w = t >> 6;
  float Wj[8];
#pragma unroll
  for (int k = 0; k < 8; ++k) Wj[k] = eW[k * HID + j];
  float bj = eb[j], msum = 0.f;
  const int TILES = N_EDGES / 256;
  for (int tile = blockIdx.x; tile < TILES; tile += gridDim.x) {
    __syncthreads();
    const float4* src = (const float4*)(eattr + (size_t)tile * 256 * FE);
    ((float4*)sA)[t] = src[t];
    ((float4*)sA)[t + 256] = src[t + 256];
    __syncthreads();
#pragma unroll 8
    for (int e = 0; e < 64; ++e) {
      const float4* ar = (const float4*)(sA + (w * 64 + e) * FE);
      float4 A0 = ar[0], A1 = ar[1];
      float acc = bj + A0.x * Wj[0] + A0.y * Wj[1] + A0.z * Wj[2] + A0.w * Wj[3]
                     + A1.x * Wj[4] + A1.y * Wj[5] + A1.z * Wj[6] + A1.w * Wj[7];
      msum += lrelu(acc, NEG_ACT);
    }
  }
  sred[t] = msum; __syncthreads();
  if (w == 0)
    partial[blockIdx.x * HID + j] = sred[j] + sred[j + 64] + sred[j + 128] + sred[j + 192];
}

__global__ __launch_bounds__(256) void k_mean(const float* __restrict__ partial,
                                              float* __restrict__ mean) {
  __shared__ float sred[256];
  int t = threadIdx.x; int j = t & 63; int w = t >> 6;
  float s = 0.f;
  for (int bk = w; bk < MEAN_BLOCKS; bk += 4) s += partial[bk * HID + j];
  sred[t] = s; __syncthreads();
  if (w == 0)
    mean[j] = (sred[j] + sred[j + 64] + sred[j + 128] + sred[j + 192]) / (float)N_EDGES;
}

// ------- K7: xl(bf16) = xh@Wl+bl, xr(f32) = xh@Wr+br -------
__global__ __launch_bounds__(256) void k_xlr(const float* __restrict__ xh,
                                             const float* __restrict__ Wl,
                                             const float* __restrict__ bl,
                                             const float* __restrict__ Wr,
                                             const float* __restrict__ br,
                                             unsigned short* __restrict__ xl_bf,
                                             float* __restrict__ xr) {
  __shared__ float sWl[HID * HID], sWr[HID * HID];
  __shared__ float srow[4][HID];
  int t = threadIdx.x;
  for (int i = t; i < HID * HID; i += 256) { sWl[i] = Wl[i]; sWr[i] = Wr[i]; }
  __syncthreads();
  int j = t & 63; int w = t >> 6;
  int v = blockIdx.x * 4 + w;
  srow[w][j] = xh[v * HID + j];
  __syncthreads();
  float accL = bl[j], accR = br[j];
#pragma unroll
  for (int k = 0; k < HID; ++k) {
    float xk = srow[w][k];
    accL += xk * sWl[k * HID + j];
    accR += xk * sWr[k * HID + j];
  }
  xl_bf[v * HID + j] = f2bf(accL);
  xr[v * HID + j] = accR;
}

// ======= K8a: edge-parallel score kernel =======
// Per 16-edge tile: MFMA1 attr->ea, MFMA2 (C=xl+xr) -> m, lrelu,
// MFMA3 head-reduce with att-masked B -> alpha[edge][head].
template <int HW>
__global__ __launch_bounds__(256) void k_score(
    const unsigned short* __restrict__ xl_bf, const float* __restrict__ xr,
    const float* __restrict__ eattr,
    const int2* __restrict__ srcperm, const int* __restrict__ dst_s,
    const float* __restrict__ eW, const float* __restrict__ eb,
    const float* __restrict__ Wed, const float* __restrict__ meanv,
    const float* __restrict__ att, float* __restrict__ alpha) {
  __shared__ __align__(16) char smem[9728];
  unsigned short* sWed = (unsigned short*)smem;                 // 8192 B
  unsigned short* sEw  = (unsigned short*)(smem + 8192);        // 1024 B
  float* sEb  = (float*)(smem + 9216);                          // 256 B
  float* sMean= (float*)(smem + 9472);                          // 256 B

  int t = threadIdx.x;
  for (int i = t; i < HID * HID; i += 256) sWed[i] = f2bf(Wed[i]);
  for (int i = t; i < FE * HID; i += 256) sEw[i] = f2bf(eW[i]);
  if (t < HID) { sEb[t] = eb[t]; sMean[t] = meanv[t]; }
  __syncthreads();

  int lane = t & 63, w = t >> 6, l15 = lane & 15, lg = lane >> 4;

  short8 bW[4][2];
#pragma unroll
  for (int jc = 0; jc < 4; ++jc)
#pragma unroll
    for (int kh = 0; kh < 2; ++kh)
#pragma unroll
      for (int i = 0; i < 8; ++i)
        bW[jc][kh][i] = (short)sWed[(8 * lg + i + 32 * kh) * HID + jc * 16 + l15];
  short8 bE[4] = {};
  if (lg == 0)
#pragma unroll
    for (int jc = 0; jc < 4; ++jc)
#pragma unroll
      for (int i = 0; i < 8; ++i)
        bE[jc][i] = (short)sEw[i * HID + jc * 16 + l15];
  float biasv[4];
  unsigned short meanbf[4];
#pragma unroll
  for (int jc = 0; jc < 4; ++jc) {
    biasv[jc] = sEb[jc * 16 + l15];
    meanbf[jc] = f2bf(sMean[jc * 16 + l15]);
  }
  // att-masked head-reduce B-frag: B[k][head] = att[k] if head(k)==head else 0
  short8 bH[2];
#pragma unroll
  for (int kh = 0; kh < 2; ++kh)
#pragma unroll
    for (int i = 0; i < 8; ++i) {
      int k = 8 * lg + i + 32 * kh;
      int hd = (HW == 16) ? (k >> 4) : 0;
      bH[kh][i] = (hd == l15) ? (short)f2bf(att[k]) : (short)0;
    }
  __syncthreads();   // all waves done with weights before slabs overwrite

  unsigned short* T = (unsigned short*)(smem + w * 2304);  // [16][72] bf16

  const int TILES = ETOT / 16;   // 103125 exact
  int stride = gridDim.x * 4;
  for (int tile = blockIdx.x * 4 + w; tile < TILES; tile += stride) {
    int base = tile * 16;
    int2 rl = srcperm[base + l15];
    int4 rA = *(const int4*)(srcperm + base + 4 * lg);      // edges 4lg,4lg+1
    int4 rB = *(const int4*)(srcperm + base + 4 * lg + 2);  // edges 4lg+2,4lg+3
    int4 d4 = *(const int4*)(dst_s + base + 4 * lg);
    int recx[4] = {rA.x, rA.z, rB.x, rB.z};
    int dstv[4] = {d4.x, d4.y, d4.z, d4.w};

    // C-init: xl[src] + xr[dst] per (edge=4lg+i, ch=jc16+l15)
    f32x4 c2[4];
#pragma unroll
    for (int jc = 0; jc < 4; ++jc)
#pragma unroll
      for (int i = 0; i < 4; ++i) {
        unsigned s = (unsigned)(recx[i] & SRC_MASK);
        c2[jc][i] = bf2f(xl_bf[(size_t)s * HID + jc * 16 + l15]) +
                    xr[(size_t)dstv[i] * HID + jc * 16 + l15];
      }

    // MFMA1: ea = attr(16x8 pad32) @ eW
    short8 a0 = {};
    if (lg == 0 && !(rl.x & SELF_FLAG)) {
      const float4* ap = (const float4*)(eattr + (size_t)rl.y * FE);
      float4 A0 = ap[0], A1 = ap[1];
      a0[0] = (short)f2bf(A0.x); a0[1] = (short)f2bf(A0.y);
      a0[2] = (short)f2bf(A0.z); a0[3] = (short)f2bf(A0.w);
      a0[4] = (short)f2bf(A1.x); a0[5] = (short)f2bf(A1.y);
      a0[6] = (short)f2bf(A1.z); a0[7] = (short)f2bf(A1.w);
    }
    f32x4 accE[4];
#pragma unroll
    for (int jc = 0; jc < 4; ++jc) {
      f32x4 z = {};
      accE[jc] = __builtin_amdgcn_mfma_f32_16x16x32_bf16(a0, bE[jc], z, 0, 0, 0);
    }
    // T1 = lrelu(ea+bias); self rows get mean(ea)
#pragma unroll
    for (int jc = 0; jc < 4; ++jc)
#pragma unroll
      for (int i = 0; i < 4; ++i) {
        unsigned short val = (recx[i] & SELF_FLAG)
            ? meanbf[jc]
            : f2bf(lrelu(accE[jc][i] + biasv[jc], NEG_ACT));
        T[(4 * lg + i) * 72 + jc * 16 + l15] = val;
      }
    __builtin_amdgcn_wave_barrier();
    asm volatile("s_waitcnt lgkmcnt(0)" ::: "memory");
    __builtin_amdgcn_sched_barrier(0);

    short8 A0 = *(const short8*)&T[l15 * 72 + 8 * lg];
    short8 A1 = *(const short8*)&T[l15 * 72 + 32 + 8 * lg];
    asm volatile("s_waitcnt lgkmcnt(0)" ::: "memory");
    __builtin_amdgcn_sched_barrier(0);

    // MFMA2: m = ea @ Wed + (xl+xr)
    f32x4 m2[4];
#pragma unroll
    for (int jc = 0; jc < 4; ++jc) {
      m2[jc] = __builtin_amdgcn_mfma_f32_16x16x32_bf16(A0, bW[jc][0], c2[jc], 0, 0, 0);
      m2[jc] = __builtin_amdgcn_mfma_f32_16x16x32_bf16(A1, bW[jc][1], m2[jc], 0, 0, 0);
    }
    // T2 = lrelu(m) (bf16), same slab
#pragma unroll
    for (int jc = 0; jc < 4; ++jc)
#pragma unroll
      for (int i = 0; i < 4; ++i)
        T[(4 * lg + i) * 72 + jc * 16 + l15] = f2bf(lrelu(m2[jc][i], NEG_ATT));
    __builtin_amdgcn_wave_barrier();
    asm volatile("s_waitcnt lgkmcnt(0)" ::: "memory");
    __builtin_amdgcn_sched_barrier(0);

    short8 A30 = *(const short8*)&T[l15 * 72 + 8 * lg];
    short8 A31 = *(const short8*)&T[l15 * 72 + 32 + 8 * lg];
    asm volatile("s_waitcnt lgkmcnt(0)" ::: "memory");
    __builtin_amdgcn_sched_barrier(0);

    // MFMA3: alpha[edge][head] = sum_ch m[edge][ch]*att[ch]*[head(ch)==head]
    f32x4 r3 = {};
    r3 = __builtin_amdgcn_mfma_f32_16x16x32_bf16(A30, bH[0], r3, 0, 0, 0);
    r3 = __builtin_amdgcn_mfma_f32_16x16x32_bf16(A31, bH[1], r3, 0, 0, 0);

    if (HW == 16) {
      if (l15 < 4) {
#pragma unroll
        for (int i = 0; i < 4; ++i)
          alpha[(size_t)(base + 4 * lg + i) * 4 + l15] = r3[i];
      }
    } else {
      if (l15 == 0) {
#pragma unroll
        for (int i = 0; i < 4; ++i)
          alpha[(size_t)(base + 4 * lg + i) * 4] = r3[i];
      }
    }
  }
}

// ======= K8b: node-parallel softmax + aggregate (no MFMA/LDS/shuffles) =======
template <int HW>
__global__ __launch_bounds__(256) void k_aggr(
    const unsigned short* __restrict__ xl_bf, const float* __restrict__ alpha,
    const int2* __restrict__ srcperm, const int* __restrict__ row_ptr,
    const float* __restrict__ cb, float* __restrict__ xo) {
  int t = threadIdx.x, lane = t & 63, w = t >> 6, l15 = lane & 15;
  int v = blockIdx.x * 4 + w;
  if (v >= N_NODES) return;
  int head = (HW == 16) ? (lane >> 4) : 0;
  float cbj = cb[lane];
  int beg = row_ptr[v], end = row_ptr[v + 1];
  float M = -3.0e38f, S = 0.f, acc = 0.f;

  for (int base = beg; base < end; base += 16) {
    int cnt = end - base; if (cnt > 16) cnt = 16;
    int eidx = base + l15; if (eidx >= end) eidx = end - 1;
    int spx = srcperm[eidx].x;
#define AGLOAD(j, idx) { \
      int raw = __builtin_amdgcn_readlane(spx, (idx)); \
      unsigned s = (unsigned)(raw & SRC_MASK); \
      xls_[j] = bf2f(xl_bf[(size_t)s * HID + lane]); \
      float av = alpha[(size_t)(base + (idx)) * 4 + head]; \
      a_[j] = ((idx) < cnt) ? av : -3.0e38f; }
#define AGROUP(G) if (cnt > 4 * (G)) { \
      float a_[4], xls_[4]; \
      AGLOAD(0, 4*(G)) AGLOAD(1, 4*(G)+1) AGLOAD(2, 4*(G)+2) AGLOAD(3, 4*(G)+3) \
      float mx = fmaxf(fmaxf(a_[0], a_[1]), fmaxf(a_[2], a_[3])); \
      float Mn = fmaxf(M, mx); \
      float sc = __expf(M - Mn); \
      acc *= sc; S *= sc; \
      { float wg = __expf(a_[0] - Mn); S += wg; acc += wg * xls_[0]; } \
      { float wg = __expf(a_[1] - Mn); S += wg; acc += wg * xls_[1]; } \
      { float wg = __expf(a_[2] - Mn); S += wg; acc += wg * xls_[2]; } \
      { float wg = __expf(a_[3] - Mn); S += wg; acc += wg * xls_[3]; } \
      M = Mn; }
    AGROUP(0) AGROUP(1) AGROUP(2) AGROUP(3)
#undef AGROUP
#undef AGLOAD
  }
  xo[(size_t)v * HID + lane] = acc / S + cbj;
}

// ---------------- K10: BN stats ----------------
__global__ __launch_bounds__(256) void k_bnstats(const float* __restrict__ xo,
                                                 float* __restrict__ bns) {
  __shared__ float s1[256], s2[256];
  int t = threadIdx.x; int j = t & 63; int r = t >> 6;
  float sum = 0.f, sq = 0.f;
  int stride = gridDim.x * 4;
  for (int v = blockIdx.x * 4 + r; v < N_NODES; v += stride) {
    float x = xo[v * HID + j];
    sum += x; sq += x * x;
  }
  s1[t] = sum; s2[t] = sq; __syncthreads();
  if (r == 0) {
    atomicAdd(&bns[j], s1[j] + s1[j + 64] + s1[j + 128] + s1[j + 192]);
    atomicAdd(&bns[64 + j], s2[j] + s2[j + 64] + s2[j + 128] + s2[j + 192]);
  }
}

// ---------------- K11: BN apply + LeakyReLU (in-place safe) ----------------
__global__ __launch_bounds__(256) void k_bnapply(const float* __restrict__ xo,
                                                 const float* __restrict__ bns,
                                                 const float* __restrict__ g,
                                                 const float* __restrict__ b,
                                                 float* __restrict__ xh) {
  int tid = blockIdx.x * 256 + threadIdx.x;
  int j = tid & 63;
  int v = tid >> 6;
  if (v >= N_NODES) return;
  const float invN = 1.f / (float)N_NODES;
  float mu = bns[j] * invN;
  float var = bns[64 + j] * invN - mu * mu;
  var = fmaxf(var, 0.f);
  float y = (xo[v * HID + j] - mu) * rsqrtf(var + EPS_BN) * g[j] + b[j];
  xh[v * HID + j] = lrelu(y, NEG_ACT);
}

// ---------------- K12: global add pool ----------------
__global__ __launch_bounds__(256) void k_pool(const float* __restrict__ xh,
                                              const int* __restrict__ batch,
                                              float* __restrict__ pooled) {
  __shared__ float lacc[4][NGR][HID];
  int t = threadIdx.x; int j = t & 63; int r = t >> 6;
  float a[NGR];
#pragma unroll
  for (int gg = 0; gg < NGR; ++gg) a[gg] = 0.f;
  int stride = gridDim.x * 4;
  for (int v = blockIdx.x * 4 + r; v < N_NODES; v += stride) {
    int g = batch[v];
    float x = xh[v * HID + j];
#pragma unroll
    for (int gg = 0; gg < NGR; ++gg) a[gg] += (g == gg) ? x : 0.f;
  }
#pragma unroll
  for (int gg = 0; gg < NGR; ++gg) lacc[r][gg][j] = a[gg];
  __syncthreads();
  if (r == 0) {
#pragma unroll
    for (int gg = 0; gg < NGR; ++gg)
      atomicAdd(&pooled[gg * HID + j],
                lacc[0][gg][j] + lacc[1][gg][j] + lacc[2][gg][j] + lacc[3][gg][j]);
  }
}

// ---------------- K13: readout ----------------
__global__ __launch_bounds__(256) void k_readout(const float* __restrict__ pooled,
                                                 const float* __restrict__ W1,
                                                 const float* __restrict__ b1,
                                                 const float* __restrict__ W2,
                                                 const float* __restrict__ b2,
                                                 float* __restrict__ out) {
  __shared__ float hid[NGR][32];
  int t = threadIdx.x;
  int g = t >> 5, q = t & 31;
  float acc = b1[q];
  for (int k = 0; k < HID; ++k) acc += pooled[g * HID + k] * W1[k * 32 + q];
  hid[g][q] = lrelu(acc, NEG_ACT);
  __syncthreads();
  if (t < NGR) {
    float o = b2[0];
    for (int q2 = 0; q2 < 32; ++q2) o += hid[t][q2] * W2[q2];
    out[t] = o;
  }
}

extern "C" void kernel_launch(void* const* d_in, const int* in_sizes, int n_in,
                              void* d_out, int out_size, void* d_ws, size_t ws_size,
                              hipStream_t stream) {
  (void)in_sizes; (void)n_in; (void)out_size; (void)ws_size;
  const float* x      = (const float*)d_in[0];
  const int*   ei     = (const int*)d_in[1];
  const float* eattr  = (const float*)d_in[2];
  const int*   batch  = (const int*)d_in[3];
  const float* node_W = (const float*)d_in[4];
  const float* node_b = (const float*)d_in[5];
  const float* eemb_W = (const float*)d_in[6];
  const float* eemb_b = (const float*)d_in[7];
  const float* ro1_W  = (const float*)d_in[35];
  const float* ro1_b  = (const float*)d_in[36];
  const float* ro2_W  = (const float*)d_in[37];
  const float* ro2_b  = (const float*)d_in[38];
  float* out = (float*)d_out;

  char* p = (char*)d_ws;
  auto alloc = [&](size_t bytes) {
    char* r = p;
    p += (bytes + 255) & ~(size_t)255;
    return r;
  };
  // --- zero zone (single memset) ---
  int*   counts = (int*)alloc((size_t)N_NODES * 4);
  float* bns    = (float*)alloc(3 * 128 * 4);
  float* pooled = (float*)alloc(NGR * HID * 4);
  size_t zero_bytes = (size_t)(p - (char*)d_ws);
  // --- fixed buffers (each written before read every call) ---
  int*   row_ptr  = (int*)alloc((size_t)(N_NODES + 1) * 4);
  int*   fill     = (int*)alloc((size_t)N_NODES * 4);
  int*   blocksum = (int*)alloc((size_t)SCAN_BLOCKS * 4);
  int*   blockoff = (int*)alloc((size_t)SCAN_BLOCKS * 4);
  int2*  srcperm  = (int2*)alloc((size_t)ETOT * 8);
  int*   dst_s    = (int*)alloc((size_t)ETOT * 4);
  float* partial  = (float*)alloc((size_t)MEAN_BLOCKS * HID * 4);
  float* meanv    = (float*)alloc(HID * 4);
  float* alpha    = (float*)alloc(((size_t)ETOT + 16) * 4 * 4);
  float* xh       = (float*)alloc((size_t)N_NODES * HID * 4);
  unsigned short* xl_bf = (unsigned short*)alloc((size_t)N_NODES * HID * 2);
  float* xr       = (float*)alloc((size_t)N_NODES * HID * 4);
  float* xo       = xh;   // alias: xh is dead between k_xlr and k_bnapply

  hipMemsetAsync(d_ws, 0, zero_bytes, stream);

  k_node_embed<<<N_NODES / 4, 256, 0, stream>>>(x, node_W, node_b, xh);
  k_hist<<<1024, 256, 0, stream>>>(ei, counts);
  k_scanA<<<SCAN_BLOCKS, 256, 0, stream>>>(counts, row_ptr, blocksum);
  k_scanB<<<1, 256, 0, stream>>>(blocksum, blockoff, row_ptr);
  k_scanC<<<SCAN_BLOCKS, 256, 0, stream>>>(row_ptr, fill, blockoff);
  k_scatter<<<1024, 256, 0, stream>>>(ei, fill, srcperm);
  k_filldst<<<(N_NODES + 3) / 4, 256, 0, stream>>>(row_ptr, dst_s);
  k_meanp<<<MEAN_BLOCKS, 256, 0, stream>>>(eattr, eemb_W, eemb_b, partial);
  k_mean<<<1, 256, 0, stream>>>(partial, meanv);

  const int ablocks = (N_NODES + 3) / 4;
  for (int L = 0; L < 3; ++L) {
    const float* Wl  = (const float*)d_in[8 + 9 * L + 0];
    const float* bl  = (const float*)d_in[8 + 9 * L + 1];
    const float* Wr  = (const float*)d_in[8 + 9 * L + 2];
    const float* br  = (const float*)d_in[8 + 9 * L + 3];
    const float* Wed = (const float*)d_in[8 + 9 * L + 4];
    const float* att = (const float*)d_in[8 + 9 * L + 5];
    const float* cb  = (const float*)d_in[8 + 9 * L + 6];
    const float* g   = (const float*)d_in[8 + 9 * L + 7];
    const float* bt  = (const float*)d_in[8 + 9 * L + 8];
    k_xlr<<<N_NODES / 4, 256, 0, stream>>>(xh, Wl, bl, Wr, br, xl_bf, xr);
    if (L < 2) {
      k_score<16><<<1024, 256, 0, stream>>>(xl_bf, xr, eattr, srcperm, dst_s,
                                            eemb_W, eemb_b, Wed, meanv, att, alpha);
      k_aggr<16><<<ablocks, 256, 0, stream>>>(xl_bf, alpha, srcperm, row_ptr, cb, xo);
    } else {
      k_score<64><<<1024, 256, 0, stream>>>(xl_bf, xr, eattr, srcperm, dst_s,
                                            eemb_W, eemb_b, Wed, meanv, att, alpha);
      k_aggr<64><<<ablocks, 256, 0, stream>>>(xl_bf, alpha, srcperm, row_ptr, cb, xo);
    }
    k_bnstats<<<256, 256, 0, stream>>>(xo, bns + L * 128);
    k_bnapply<<<N_NODES * HID / 256, 256, 0, stream>>>(xo, bns + L * 128, g, bt, xh);
  }

  k_pool<<<64, 256, 0, stream>>>(xh, batch, pooled);
  k_readout<<<1, 256, 0, stream>>>(pooled, ro1_W, ro1_b, ro2_W, ro2_b, out);
}